// Round 5
// baseline (195.531 us; speedup 1.0000x reference)
//
#include <hip/hip_runtime.h>

// PositionAttentionModule: B=2,C=64,C8=8,H=W=96,N=9216
// Round 5: transposed QK (D[m][qrow]) so P stays in registers as the PV
// B-operand; V A-frags read with permuted k-order (ds_read2_b64 pairs).
// No P LDS round-trip, no k_s (K from global/L2). PACC in [c][n]-major.
// SPLIT chosen at runtime from ws_size (8 -> 6 -> 4).

#define BN 2
#define CC 64
#define C8K 8
#define NN 9216
#define MCHUNK 192
#define TQ 128                // query rows per block (4 waves x 32)
#define NBLKQ (NN / TQ)       // 72
#define PREP_PX 64
#define SHIFT 12.0f
#define PSTR 200              // shorts; 400B row: %16==0, 4-way worst on frag reads

typedef __attribute__((ext_vector_type(8))) short short8;
typedef __attribute__((ext_vector_type(16))) float f32x16;

// float offsets into workspace
#define OFF_QB 0                                   // bf16 [b][n][8]
#define OFF_KT (OFF_QB + BN * NN * C8K / 2)        // bf16 [b][m][8]
#define OFF_VT (OFF_KT + BN * NN * C8K / 2)        // bf16 [b][c][m]
#define OFF_PACC (OFF_VT + BN * NN * CC / 2)       // fp32 [sp][b][c][n]
// PSUM follows PACC (runtime-sized): [sp][b][n]

static __device__ inline unsigned f2bf(float x) {
    unsigned u = __builtin_bit_cast(unsigned, x);
    return (u + 0x7fff + ((u >> 16) & 1)) >> 16;   // RNE
}

// pack two f32 -> bf16 pair (round half up: 1 add each + 1 v_perm)
static __device__ inline unsigned pk_bf2(float lo, float hi) {
    unsigned ulo = __builtin_bit_cast(unsigned, lo) + 0x8000u;
    unsigned uhi = __builtin_bit_cast(unsigned, hi) + 0x8000u;
    return __builtin_amdgcn_perm(uhi, ulo, 0x07060302u);
}

__global__ __launch_bounds__(256) void pam_prep(
    const float* __restrict__ fm, const float* __restrict__ depth,
    const float* __restrict__ wa, const float* __restrict__ ba,
    const float* __restrict__ wb, const float* __restrict__ bb,
    const float* __restrict__ wc, const float* __restrict__ bc,
    const float* __restrict__ wd, const float* __restrict__ bd,
    unsigned short* __restrict__ Qb, unsigned short* __restrict__ Kt,
    unsigned short* __restrict__ Vt)
{
    __shared__ float s_wd[CC * CC];
    __shared__ float s_wb[C8K * CC], s_wc[C8K * CC];
    __shared__ float s_wa[CC], s_ba[CC], s_bd[CC];
    __shared__ float s_bb[C8K], s_bc[C8K];
    __shared__ float qp[4][PREP_PX][C8K + 1];

    int t = threadIdx.x;
    for (int i = t; i < CC * CC; i += 256) s_wd[i] = wd[i];
    for (int i = t; i < C8K * CC; i += 256) { s_wb[i] = wb[i]; s_wc[i] = wc[i]; }
    if (t < CC) { s_wa[t] = wa[t]; s_ba[t] = ba[t]; s_bd[t] = bd[t]; }
    if (t < C8K) { s_bb[t] = bb[t]; s_bc[t] = bc[t]; }
    __syncthreads();

    int px0 = blockIdx.x * PREP_PX;
    int b = px0 / NN;
    int m0 = px0 - b * NN;
    int px = t & 63, w = t >> 6;
    int m = m0 + px;
    int gidx = px0 + px;

    float d = depth[gidx];
    float df[CC];
#pragma unroll
    for (int i = 0; i < CC; ++i) df[i] = fmaxf(s_wa[i] * d + s_ba[i], 0.0f);

#pragma unroll 4
    for (int cc = 0; cc < 16; ++cc) {
        int c = w * 16 + cc;
        float acc = s_bd[c];
#pragma unroll
        for (int i = 0; i < CC; i += 4) {
            float4 wv = *(const float4*)&s_wd[c * CC + i];
            acc += wv.x * df[i] + wv.y * df[i + 1] + wv.z * df[i + 2] + wv.w * df[i + 3];
        }
        Vt[(b * CC + c) * NN + m] = (unsigned short)f2bf(acc);
    }

    {
        float k0 = s_bc[2 * w], k1 = s_bc[2 * w + 1];
#pragma unroll
        for (int i = 0; i < CC; ++i) {
            k0 += s_wc[(2 * w) * CC + i] * df[i];
            k1 += s_wc[(2 * w + 1) * CC + i] * df[i];
        }
        unsigned pkv = f2bf(k0) | (f2bf(k1) << 16);
        *(unsigned*)&Kt[(b * NN + m) * C8K + 2 * w] = pkv;
    }

    {
        float q[C8K];
#pragma unroll
        for (int k = 0; k < C8K; ++k) q[k] = (w == 0) ? s_bb[k] : 0.0f;
#pragma unroll
        for (int ii = 0; ii < 16; ++ii) {
            int i = w * 16 + ii;
            float f = fm[(b * CC + i) * NN + m];
#pragma unroll
            for (int k = 0; k < C8K; ++k) q[k] += s_wb[k * CC + i] * f;
        }
#pragma unroll
        for (int k = 0; k < C8K; ++k) qp[w][px][k] = q[k];
    }
    __syncthreads();
    {
        int px2 = t >> 2, k2 = (t & 3) * 2;
        float a0 = qp[0][px2][k2] + qp[1][px2][k2] + qp[2][px2][k2] + qp[3][px2][k2];
        float a1 = qp[0][px2][k2 + 1] + qp[1][px2][k2 + 1] + qp[2][px2][k2 + 1] + qp[3][px2][k2 + 1];
        unsigned pkv = f2bf(a0) | (f2bf(a1) << 16);
        *(unsigned*)&Qb[(px0 + px2) * C8K + k2] = pkv;
    }
}

// grid (72, SPLIT, B), block 256 = 4 waves; wave w -> qrows [w*32, w*32+32).
__global__ __launch_bounds__(256, 4) void pam_attn(
    const unsigned short* __restrict__ Qb, const unsigned short* __restrict__ Kt,
    const unsigned short* __restrict__ Vt,
    float* __restrict__ PACC, float* __restrict__ PSUM,
    int m_range)
{
    __shared__ unsigned short v_s[CC * PSTR];   // 25.6 KB bf16 [c][m]

    int t = threadIdx.x;
    int n0 = blockIdx.x * TQ;
    int split = blockIdx.y;
    int b = blockIdx.z;
    int m_start = split * m_range;
    int nchunk = m_range / MCHUNK;

    int lane = t & 63, w = t >> 6;
    int l31 = lane & 31, half = lane >> 5;

    // loop-invariant B-frag for QK: Q[qrow=l31][k]; half1 k-slots are zero.
    short8 bq = {};
    if (lane < 32)
        bq = *(const short8*)&Qb[(b * NN + n0 + w * 32 + l31) * C8K];

    f32x16 acc0 = {}, acc1 = {};
    float rsum = 0.0f;

    // V A-frag base pointers (this lane's channel rows, permuted k-order)
    const unsigned short* vr0 = &v_s[l31 * PSTR + half * 4];
    const unsigned short* vr1 = &v_s[(32 + l31) * PSTR + half * 4];

    int vrow = t >> 2, vsl = t & 3;   // staging: row, 16B-segment lane

    for (int ch = 0; ch < nchunk; ++ch) {
        int m0 = m_start + ch * MCHUNK;
        __syncthreads();   // prior chunk's v_s reads complete
        // ---- stage V chunk: 64 rows x 192 shorts ----
        {
            const unsigned short* gsrc = &Vt[(b * CC + vrow) * NN + m0 + vsl * 8];
            unsigned short* ldst = &v_s[vrow * PSTR + vsl * 8];
#pragma unroll
            for (int i = 0; i < 6; ++i)
                *(uint4*)(ldst + i * 32) = *(const uint4*)(gsrc + i * 32);
        }
        __syncthreads();

#pragma unroll
        for (int mt = 0; mt < 6; ++mt) {
            // ---- QK^T transposed: A = K rows (global, L2-hot), B = Q ----
            short8 aK = {};
            if (lane < 32)
                aK = *(const short8*)&Kt[(b * NN + m0 + mt * 32 + l31) * C8K];
            f32x16 s = __builtin_amdgcn_mfma_f32_32x32x16_bf16(aK, bq, (f32x16){}, 0, 0, 0);
            // ---- exp + rowsum + pack (all in-register) ----
            unsigned qd[8];
#pragma unroll
            for (int i = 0; i < 8; ++i) {
                float e0 = __expf(s[2 * i] - SHIFT);
                float e1 = __expf(s[2 * i + 1] - SHIFT);
                rsum += e0 + e1;
                qd[i] = pk_bf2(e0, e1);
            }
            // ---- PV: B = qd verbatim; A = v_s with permuted k-order ----
#pragma unroll
            for (int ks = 0; ks < 2; ++ks) {
                union { unsigned u[4]; short8 s8; } Bp;
#pragma unroll
                for (int i = 0; i < 4; ++i) Bp.u[i] = qd[ks * 4 + i];
                const int off = mt * 32 + ks * 16;
                union { unsigned long long d[2]; short8 s8; } A0, A1;
                A0.d[0] = *(const unsigned long long*)(vr0 + off);
                A0.d[1] = *(const unsigned long long*)(vr0 + off + 8);
                A1.d[0] = *(const unsigned long long*)(vr1 + off);
                A1.d[1] = *(const unsigned long long*)(vr1 + off + 8);
                acc0 = __builtin_amdgcn_mfma_f32_32x32x16_bf16(A0.s8, Bp.s8, acc0, 0, 0, 0);
                acc1 = __builtin_amdgcn_mfma_f32_32x32x16_bf16(A1.s8, Bp.s8, acc1, 0, 0, 0);
            }
        }
    }

    // ---- epilogue ----
    // row sums: halves hold disjoint m-subsets of the same qrow=l31 column
    rsum += __shfl_xor(rsum, 32);
    if (lane < 32)
        PSUM[(split * BN + b) * NN + n0 + w * 32 + l31] = rsum;

    // acc: D[c][qrow]: lane l31 = qrow, reg -> c = 8*(reg>>2)+(reg&3)+4*half
    {
        int slabc = (split * BN + b) * CC;
        int nidx = n0 + w * 32 + l31;
#pragma unroll
        for (int reg = 0; reg < 16; ++reg) {
            int c = 8 * (reg >> 2) + (reg & 3) + 4 * half;
            PACC[(slabc + c) * NN + nidx] = acc0[reg];
            PACC[(slabc + 32 + c) * NN + nidx] = acc1[reg];
        }
    }
}

// out[b][c][n] = sum_sp PACC[sp][b][c][n] / sum_sp PSUM[sp][b][n]
__global__ __launch_bounds__(256) void pam_norm(
    const float* __restrict__ PACC, const float* __restrict__ PSUM,
    float* __restrict__ out, int S)
{
    int t = threadIdx.x;
    int n = blockIdx.x * 64 + (t & 63);
    int b = blockIdx.y;
    int cg = t >> 6;

    float s = 0.0f;
    for (int sp = 0; sp < S; ++sp) s += PSUM[(sp * BN + b) * NN + n];
    float inv = 1.0f / s;

    for (int cc = 0; cc < 16; ++cc) {
        int c = cg * 16 + cc;
        float a = 0.0f;
        for (int sp = 0; sp < S; ++sp)
            a += PACC[((sp * BN + b) * CC + c) * NN + n];
        out[(b * CC + c) * NN + n] = a * inv;
    }
}

extern "C" void kernel_launch(void* const* d_in, const int* in_sizes, int n_in,
                              void* d_out, int out_size, void* d_ws, size_t ws_size,
                              hipStream_t stream) {
    const float* fm    = (const float*)d_in[0];
    const float* depth = (const float*)d_in[1];
    const float* wa    = (const float*)d_in[2];
    const float* ba    = (const float*)d_in[3];
    const float* wb    = (const float*)d_in[4];
    const float* bb    = (const float*)d_in[5];
    const float* wc    = (const float*)d_in[6];
    const float* bc    = (const float*)d_in[7];
    const float* wd    = (const float*)d_in[8];
    const float* bd    = (const float*)d_in[9];
    float* out = (float*)d_out;

    float* ws = (float*)d_ws;
    unsigned short* Qb = (unsigned short*)(ws + OFF_QB);
    unsigned short* Kt = (unsigned short*)(ws + OFF_KT);
    unsigned short* Vt = (unsigned short*)(ws + OFF_VT);
    float* PACC = ws + OFF_PACC;

    // pick largest split that fits the workspace (PACC + PSUM after OFF_PACC)
    int S = 8;
    while (S > 4) {
        size_t need = ((size_t)OFF_PACC + (size_t)S * BN * NN * CC + (size_t)S * BN * NN) * 4;
        if (need <= ws_size) break;
        S -= 2;
    }
    float* PSUM = PACC + (size_t)S * BN * NN * CC;
    int m_range = NN / S;   // S in {8,6,4} -> {1152,1536,2304}, all % 192 == 0

    pam_prep<<<dim3((BN * NN) / PREP_PX), 256, 0, stream>>>(
        fm, depth, wa, ba, wb, bb, wc, bc, wd, bd, Qb, Kt, Vt);
    pam_attn<<<dim3(NBLKQ, S, BN), 256, 0, stream>>>(Qb, Kt, Vt, PACC, PSUM, m_range);
    pam_norm<<<dim3(NN / 64, BN), 256, 0, stream>>>(PACC, PSUM, out, S);
}

// Round 6
// 147.629 us; speedup vs baseline: 1.3245x; 1.3245x over previous
//
#include <hip/hip_runtime.h>

// PositionAttentionModule: B=2,C=64,C8=8,H=W=96,N=9216
// Round 6: R5 structure (transposed QK, P in regs, permuted-k V frags) +
// S=12 splits, batch K prefetch, reg-staged V, PSTR=196 (conflict-free b64),
// bf16 PACC. launch_bounds(256,4) -> 4 blocks/CU.

#define BN 2
#define CC 64
#define C8K 8
#define NN 9216
#define MCHUNK 192
#define TQ 128                // query rows per block (4 waves x 32)
#define NBLKQ (NN / TQ)       // 72
#define PREP_PX 64
#define SHIFT 12.0f
#define PSTR 196              // shorts; 392B row: dword-pair stride 49 (odd mod 16)

typedef __attribute__((ext_vector_type(8))) short short8;
typedef __attribute__((ext_vector_type(16))) float f32x16;

// float offsets into workspace
#define OFF_QB 0                                   // bf16 [b][n][8]
#define OFF_KT (OFF_QB + BN * NN * C8K / 2)        // bf16 [b][m][8]
#define OFF_VT (OFF_KT + BN * NN * C8K / 2)        // bf16 [b][c][m]
#define OFF_PACC (OFF_VT + BN * NN * CC / 2)       // bf16 [sp][b][c][n]
// PSUM (fp32 [sp][b][n]) follows PACC

static __device__ inline unsigned f2bf(float x) {
    unsigned u = __builtin_bit_cast(unsigned, x);
    return (u + 0x7fff + ((u >> 16) & 1)) >> 16;   // RNE
}

// pack two f32 -> bf16 pair (round half up: 1 add each + 1 v_perm)
static __device__ inline unsigned pk_bf2(float lo, float hi) {
    unsigned ulo = __builtin_bit_cast(unsigned, lo) + 0x8000u;
    unsigned uhi = __builtin_bit_cast(unsigned, hi) + 0x8000u;
    return __builtin_amdgcn_perm(uhi, ulo, 0x07060302u);
}

__global__ __launch_bounds__(256) void pam_prep(
    const float* __restrict__ fm, const float* __restrict__ depth,
    const float* __restrict__ wa, const float* __restrict__ ba,
    const float* __restrict__ wb, const float* __restrict__ bb,
    const float* __restrict__ wc, const float* __restrict__ bc,
    const float* __restrict__ wd, const float* __restrict__ bd,
    unsigned short* __restrict__ Qb, unsigned short* __restrict__ Kt,
    unsigned short* __restrict__ Vt)
{
    __shared__ float s_wd[CC * CC];
    __shared__ float s_wb[C8K * CC], s_wc[C8K * CC];
    __shared__ float s_wa[CC], s_ba[CC], s_bd[CC];
    __shared__ float s_bb[C8K], s_bc[C8K];
    __shared__ float qp[4][PREP_PX][C8K + 1];

    int t = threadIdx.x;
    for (int i = t; i < CC * CC; i += 256) s_wd[i] = wd[i];
    for (int i = t; i < C8K * CC; i += 256) { s_wb[i] = wb[i]; s_wc[i] = wc[i]; }
    if (t < CC) { s_wa[t] = wa[t]; s_ba[t] = ba[t]; s_bd[t] = bd[t]; }
    if (t < C8K) { s_bb[t] = bb[t]; s_bc[t] = bc[t]; }
    __syncthreads();

    int px0 = blockIdx.x * PREP_PX;
    int b = px0 / NN;
    int m0 = px0 - b * NN;
    int px = t & 63, w = t >> 6;
    int m = m0 + px;
    int gidx = px0 + px;

    float d = depth[gidx];
    float df[CC];
#pragma unroll
    for (int i = 0; i < CC; ++i) df[i] = fmaxf(s_wa[i] * d + s_ba[i], 0.0f);

#pragma unroll 4
    for (int cc = 0; cc < 16; ++cc) {
        int c = w * 16 + cc;
        float acc = s_bd[c];
#pragma unroll
        for (int i = 0; i < CC; i += 4) {
            float4 wv = *(const float4*)&s_wd[c * CC + i];
            acc += wv.x * df[i] + wv.y * df[i + 1] + wv.z * df[i + 2] + wv.w * df[i + 3];
        }
        Vt[(b * CC + c) * NN + m] = (unsigned short)f2bf(acc);
    }

    {
        float k0 = s_bc[2 * w], k1 = s_bc[2 * w + 1];
#pragma unroll
        for (int i = 0; i < CC; ++i) {
            k0 += s_wc[(2 * w) * CC + i] * df[i];
            k1 += s_wc[(2 * w + 1) * CC + i] * df[i];
        }
        unsigned pkv = f2bf(k0) | (f2bf(k1) << 16);
        *(unsigned*)&Kt[(b * NN + m) * C8K + 2 * w] = pkv;
    }

    {
        float q[C8K];
#pragma unroll
        for (int k = 0; k < C8K; ++k) q[k] = (w == 0) ? s_bb[k] : 0.0f;
#pragma unroll
        for (int ii = 0; ii < 16; ++ii) {
            int i = w * 16 + ii;
            float f = fm[(b * CC + i) * NN + m];
#pragma unroll
            for (int k = 0; k < C8K; ++k) q[k] += s_wb[k * CC + i] * f;
        }
#pragma unroll
        for (int k = 0; k < C8K; ++k) qp[w][px][k] = q[k];
    }
    __syncthreads();
    {
        int px2 = t >> 2, k2 = (t & 3) * 2;
        float a0 = qp[0][px2][k2] + qp[1][px2][k2] + qp[2][px2][k2] + qp[3][px2][k2];
        float a1 = qp[0][px2][k2 + 1] + qp[1][px2][k2 + 1] + qp[2][px2][k2 + 1] + qp[3][px2][k2 + 1];
        unsigned pkv = f2bf(a0) | (f2bf(a1) << 16);
        *(unsigned*)&Qb[(px0 + px2) * C8K + k2] = pkv;
    }
}

// grid (72, S, B), block 256 = 4 waves; wave w -> qrows [w*32, w*32+32).
__global__ __launch_bounds__(256, 4) void pam_attn(
    const unsigned short* __restrict__ Qb, const unsigned short* __restrict__ Kt,
    const unsigned short* __restrict__ Vt,
    unsigned short* __restrict__ PACC, float* __restrict__ PSUM,
    int m_range)
{
    __shared__ unsigned short v_s[CC * PSTR];   // 24.5 KB bf16 [c][m]

    int t = threadIdx.x;
    int n0 = blockIdx.x * TQ;
    int split = blockIdx.y;
    int b = blockIdx.z;
    int m_start = split * m_range;
    int nchunk = m_range / MCHUNK;

    int lane = t & 63, w = t >> 6;
    int l31 = lane & 31, half = lane >> 5;

    // loop-invariant B-frag for QK: Q[qrow=l31][k]; half1 k-slots are zero.
    short8 bq = {};
    if (lane < 32)
        bq = *(const short8*)&Qb[(b * NN + n0 + w * 32 + l31) * C8K];

    f32x16 acc0 = {}, acc1 = {};
    float rsum = 0.0f;

    // V A-frag base pointers (this lane's channel rows, permuted k-order)
    const unsigned short* vr0 = &v_s[l31 * PSTR + half * 4];
    const unsigned short* vr1 = &v_s[(32 + l31) * PSTR + half * 4];

    int vrow = t >> 2, vsl = t & 3;   // staging: channel row, 16B-segment

    for (int ch = 0; ch < nchunk; ++ch) {
        int m0 = m_start + ch * MCHUNK;
        __syncthreads();   // prior chunk's v_s reads complete
        // ---- V loads to regs first (independent, latencies overlap) ----
        ulonglong2 vbuf[6];
        {
            const unsigned short* gsrc = &Vt[(b * CC + vrow) * NN + m0 + vsl * 8];
#pragma unroll
            for (int i = 0; i < 6; ++i)
                vbuf[i] = *(const ulonglong2*)(gsrc + i * 32);
        }
        // ---- batch K-frag loads for all 6 m-tiles (L2-hot) ----
        short8 aK[6];
#pragma unroll
        for (int mt = 0; mt < 6; ++mt) aK[mt] = (short8){};
        if (lane < 32) {
#pragma unroll
            for (int mt = 0; mt < 6; ++mt)
                aK[mt] = *(const short8*)&Kt[(b * NN + m0 + mt * 32 + l31) * C8K];
        }
        // ---- LDS writes (8B pieces: 392B rows are 8B-aligned) ----
        {
            unsigned long long* ldst =
                (unsigned long long*)&v_s[vrow * PSTR + vsl * 8];
#pragma unroll
            for (int i = 0; i < 6; ++i) {
                ldst[i * 8 + 0] = vbuf[i].x;
                ldst[i * 8 + 1] = vbuf[i].y;
            }
        }
        __syncthreads();

#pragma unroll
        for (int mt = 0; mt < 6; ++mt) {
            // ---- QK^T transposed: D[m][qrow] ----
            f32x16 s = __builtin_amdgcn_mfma_f32_32x32x16_bf16(aK[mt], bq, (f32x16){}, 0, 0, 0);
            // ---- exp + rowsum + pack (in-register) ----
            unsigned qd[8];
#pragma unroll
            for (int i = 0; i < 8; ++i) {
                float e0 = __expf(s[2 * i] - SHIFT);
                float e1 = __expf(s[2 * i + 1] - SHIFT);
                rsum += e0 + e1;
                qd[i] = pk_bf2(e0, e1);
            }
            // ---- PV: B = qd verbatim; A = v_s with permuted k-order ----
#pragma unroll
            for (int ks = 0; ks < 2; ++ks) {
                union { unsigned u[4]; short8 s8; } Bp;
#pragma unroll
                for (int i = 0; i < 4; ++i) Bp.u[i] = qd[ks * 4 + i];
                const int off = mt * 32 + ks * 16;
                union { unsigned long long d[2]; short8 s8; } A0, A1;
                A0.d[0] = *(const unsigned long long*)(vr0 + off);
                A0.d[1] = *(const unsigned long long*)(vr0 + off + 8);
                A1.d[0] = *(const unsigned long long*)(vr1 + off);
                A1.d[1] = *(const unsigned long long*)(vr1 + off + 8);
                acc0 = __builtin_amdgcn_mfma_f32_32x32x16_bf16(A0.s8, Bp.s8, acc0, 0, 0, 0);
                acc1 = __builtin_amdgcn_mfma_f32_32x32x16_bf16(A1.s8, Bp.s8, acc1, 0, 0, 0);
            }
        }
    }

    // ---- epilogue ----
    rsum += __shfl_xor(rsum, 32);
    if (lane < 32)
        PSUM[(split * BN + b) * NN + n0 + w * 32 + l31] = rsum;

    // D[c][qrow]: lane l31 = qrow (n), reg -> c = 8*(reg>>2)+(reg&3)+4*half
    {
        int slabc = (split * BN + b) * CC;
        int nidx = n0 + w * 32 + l31;
#pragma unroll
        for (int reg = 0; reg < 16; ++reg) {
            int c = 8 * (reg >> 2) + (reg & 3) + 4 * half;
            PACC[(slabc + c) * NN + nidx] = (unsigned short)f2bf(acc0[reg]);
            PACC[(slabc + 32 + c) * NN + nidx] = (unsigned short)f2bf(acc1[reg]);
        }
    }
}

// out[b][c][n] = sum_sp PACC[sp][b][c][n] / sum_sp PSUM[sp][b][n]
__global__ __launch_bounds__(256) void pam_norm(
    const unsigned short* __restrict__ PACC, const float* __restrict__ PSUM,
    float* __restrict__ out, int S)
{
    __shared__ float s_inv[64];
    int t = threadIdx.x;
    int n0 = blockIdx.x * 64;
    int b = blockIdx.y;
    if (t < 64) {
        float s = 0.0f;
        for (int sp = 0; sp < S; ++sp) s += PSUM[(sp * BN + b) * NN + n0 + t];
        s_inv[t] = 1.0f / s;
    }
    __syncthreads();

    int c = t >> 2, ng = t & 3;       // channel, 16-n group
    int nb = n0 + ng * 16;
    float a[16];
#pragma unroll
    for (int j = 0; j < 16; ++j) a[j] = 0.0f;

    for (int sp = 0; sp < S; ++sp) {
        const unsigned short* p = &PACC[((sp * BN + b) * CC + c) * NN + nb];
        uint4 u0 = *(const uint4*)p;
        uint4 u1 = *(const uint4*)(p + 8);
        const unsigned uu[8] = {u0.x, u0.y, u0.z, u0.w, u1.x, u1.y, u1.z, u1.w};
#pragma unroll
        for (int i = 0; i < 8; ++i) {
            a[2 * i]     += __builtin_bit_cast(float, uu[i] << 16);
            a[2 * i + 1] += __builtin_bit_cast(float, uu[i] & 0xffff0000u);
        }
    }
    float* o = &out[(b * CC + c) * NN + nb];
#pragma unroll
    for (int j4 = 0; j4 < 4; ++j4) {
        float4 v;
        v.x = a[j4 * 4 + 0] * s_inv[ng * 16 + j4 * 4 + 0];
        v.y = a[j4 * 4 + 1] * s_inv[ng * 16 + j4 * 4 + 1];
        v.z = a[j4 * 4 + 2] * s_inv[ng * 16 + j4 * 4 + 2];
        v.w = a[j4 * 4 + 3] * s_inv[ng * 16 + j4 * 4 + 3];
        *(float4*)(o + j4 * 4) = v;
    }
}

extern "C" void kernel_launch(void* const* d_in, const int* in_sizes, int n_in,
                              void* d_out, int out_size, void* d_ws, size_t ws_size,
                              hipStream_t stream) {
    const float* fm    = (const float*)d_in[0];
    const float* depth = (const float*)d_in[1];
    const float* wa    = (const float*)d_in[2];
    const float* ba    = (const float*)d_in[3];
    const float* wb    = (const float*)d_in[4];
    const float* bb    = (const float*)d_in[5];
    const float* wc    = (const float*)d_in[6];
    const float* bc    = (const float*)d_in[7];
    const float* wd    = (const float*)d_in[8];
    const float* bd    = (const float*)d_in[9];
    float* out = (float*)d_out;

    float* ws = (float*)d_ws;
    unsigned short* Qb = (unsigned short*)(ws + OFF_QB);
    unsigned short* Kt = (unsigned short*)(ws + OFF_KT);
    unsigned short* Vt = (unsigned short*)(ws + OFF_VT);
    unsigned short* PACC = (unsigned short*)(ws + OFF_PACC);

    // pick largest split whose PACC(bf16)+PSUM fit: 12 -> 8 -> 4
    int S = 12;
    while (S > 4) {
        size_t need = (size_t)OFF_PACC * 4
                    + (size_t)S * BN * NN * CC * 2      // PACC bf16
                    + (size_t)S * BN * NN * 4;          // PSUM fp32
        if (need <= ws_size) break;
        S -= 4;
    }
    float* PSUM = (float*)(PACC + (size_t)S * BN * NN * CC);
    int m_range = NN / S;   // 12->768, 8->1152, 4->2304; all % 192 == 0

    pam_prep<<<dim3((BN * NN) / PREP_PX), 256, 0, stream>>>(
        fm, depth, wa, ba, wb, bb, wc, bc, wd, bd, Qb, Kt, Vt);
    pam_attn<<<dim3(NBLKQ, S, BN), 256, 0, stream>>>(Qb, Kt, Vt, PACC, PSUM, m_range);
    pam_norm<<<dim3(NN / 64, BN), 256, 0, stream>>>(PACC, PSUM, out, S);
}